// Round 1
// baseline (29.954 us; speedup 1.0000x reference)
//
#include <hip/hip_runtime.h>
#include <math.h>

#define BATCH 4
#define NPTS  32
#define IMH   512
#define IMW   512
#define HB    64
#define TW    32
#define TH    8

// ---------------- Kernel 1: natural cubic spline -> per-stroke params ----------------
// One block (1 wave) per batch. Lane k (k<32) holds node k. Thomas algorithm via shuffles.
// params[(b*NPTS+k)*8 + {0..7}] = {x, y, cos(th), sin(th), 1/scale, cull_radius, active, pad}
__global__ __launch_bounds__(64) void spline_kernel(
    const float* __restrict__ traj, float* __restrict__ params) {
  int b = blockIdx.x;
  int lane = threadIdx.x;
  const float* tb = traj + b * 4 * NPTS;
  float tsv = 0.f, xv = 0.f, yv = 0.f, zv = 0.f;
  if (lane < NPTS) {
    tsv = tb[0 * NPTS + lane];
    xv  = tb[1 * NPTS + lane];
    yv  = tb[2 * NPTS + lane];
    zv  = tb[3 * NPTS + lane];
  }
  // h[k] = ts[k+1]-ts[k], slopes[k] = (q[k+1]-q[k])/h[k]   (valid for k < 31)
  float ts1 = __shfl_down(tsv, 1);
  float x1  = __shfl_down(xv, 1);
  float y1  = __shfl_down(yv, 1);
  float hv  = ts1 - tsv;
  float sxv = (x1 - xv) / hv;
  float syv = (y1 - yv) / hv;

  // Thomas forward sweep over interior unknowns i = 1..30 (M[0]=M[31]=0).
  // All lanes redundantly compute the (uniform) recurrence scalars; lane i keeps cp[i], d[i].
  float cpv = 0.f, ddx = 0.f, ddy = 0.f;
  float cp_prev = 0.f, dx_prev = 0.f, dy_prev = 0.f;
  for (int i = 1; i <= NPTS - 2; ++i) {
    float a  = __shfl(hv, i - 1);
    float hi = __shfl(hv, i);
    float rx = 6.0f * (__shfl(sxv, i) - __shfl(sxv, i - 1));
    float ry = 6.0f * (__shfl(syv, i) - __shfl(syv, i - 1));
    float bb = 2.0f * (a + hi);
    float m  = bb - a * cp_prev;
    float cpi = hi / m;
    float dxi = (rx - a * dx_prev) / m;
    float dyi = (ry - a * dy_prev) / m;
    if (lane == i) { cpv = cpi; ddx = dxi; ddy = dyi; }
    cp_prev = cpi; dx_prev = dxi; dy_prev = dyi;
  }
  // Back substitution: lane i keeps M[i].
  float Mxv = 0.f, Myv = 0.f;
  float mx_next = 0.f, my_next = 0.f;
  for (int i = NPTS - 2; i >= 1; --i) {
    float cpi = __shfl(cpv, i);
    float dxi = __shfl(ddx, i);
    float dyi = __shfl(ddy, i);
    float mxi = dxi - cpi * mx_next;
    float myi = dyi - cpi * my_next;
    if (lane == i) { Mxv = mxi; Myv = myi; }
    mx_next = mxi; my_next = myi;
  }
  // Node derivatives (all shuffles executed uniformly, before any divergence).
  float Mx1  = __shfl_down(Mxv, 1);
  float My1  = __shfl_down(Myv, 1);
  float sx30 = __shfl(sxv, NPTS - 2);
  float sy30 = __shfl(syv, NPTS - 2);
  float h30  = __shfl(hv,  NPTS - 2);
  float Mx30 = __shfl(Mxv, NPTS - 2);
  float My30 = __shfl(Myv, NPTS - 2);
  float Mx31 = __shfl(Mxv, NPTS - 1);
  float My31 = __shfl(Myv, NPTS - 1);

  float dX, dY;
  if (lane < NPTS - 1) {
    dX = sxv - hv * (2.0f * Mxv + Mx1) / 6.0f;
    dY = syv - hv * (2.0f * Myv + My1) / 6.0f;
  } else {
    dX = sx30 + h30 * (2.0f * Mx31 + Mx30) / 6.0f;
    dY = sy30 + h30 * (2.0f * My31 + My30) / 6.0f;
  }
  if (lane < NPTS) {
    // theta = -atan2(dY, dX) -> cos = dX/r, sin = -dY/r
    float r2 = dX * dX + dY * dY;
    float c, s;
    if (r2 > 0.f) { float inv = 1.0f / sqrtf(r2); c = dX * inv; s = -dY * inv; }
    else          { c = 1.f; s = 0.f; }
    float scale = fminf(fmaxf(zv, 0.001f), 1.0f);
    float* p = params + (b * NPTS + lane) * 8;
    p[0] = xv;
    p[1] = yv;
    p[2] = c;
    p[3] = s;
    p[4] = 1.0f / scale;
    // max image-space reach of nonzero contribution: scale*sqrt(2)*32.5 = scale*45.97; margin added
    p[5] = scale * 47.4f + 1.5f;
    p[6] = (zv > 0.f) ? 1.f : 0.f;
    p[7] = 0.f;
  }
}

// ---------------- Kernel 2: composite 32 strokes per pixel ----------------
__global__ __launch_bounds__(256) void paint_kernel(
    const float* __restrict__ images, const float* __restrict__ params,
    const float* __restrict__ colors, const float* __restrict__ brush,
    float* __restrict__ out) {
  __shared__ float sA[HB][HB + 1];   // brush alpha, padded stride (bank-conflict-free)
  __shared__ float sp[NPTS][8];
  __shared__ float scol[4];
  int b = blockIdx.z;
  int t = threadIdx.x;
  for (int i = t; i < HB * HB; i += 256) sA[i >> 6][i & (HB - 1)] = brush[3 * HB * HB + i];
  if (t < NPTS * 8) ((float*)sp)[t] = params[b * NPTS * 8 + t];
  if (t < 4) scol[t] = colors[b * 4 + t];
  __syncthreads();

  int tx = t % TW, ty = t / TW;
  int c0 = blockIdx.x * TW, r0 = blockIdx.y * TH;
  int col = c0 + tx, row = r0 + ty;
  float fcx = (float)col, fry = (float)row;
  size_t plane = (size_t)IMH * IMW;
  size_t base = (size_t)b * 4 * plane + (size_t)row * IMW + col;

  float i3 = images[base + 3 * plane];
  float g0 = 1.f - images[base];
  float g1 = 1.f - images[base + plane];
  float g2 = 1.f - images[base + 2 * plane];
  float cr = scol[0], cg = scol[1], cb = scol[2], ca = scol[3];

  float tcx0 = (float)c0, tcx1 = (float)(c0 + TW - 1);
  float try0 = (float)r0, try1 = (float)(r0 + TH - 1);

  #pragma unroll 1
  for (int k = 0; k < NPTS; ++k) {
    if (sp[k][6] == 0.f) continue;                 // inactive stroke (exact: where(on,...))
    float px = sp[k][0], py = sp[k][1], R = sp[k][5];
    // Block-uniform bounding-box cull (exact no-op outside: contribution is identically 0).
    if (px + R < tcx0 || px - R > tcx1 || py + R < try0 || py - R > try1) continue;

    float dx = fcx - px, dy = fry - py;
    float cth = sp[k][2], sth = sp[k][3], isc = sp[k][4];
    float lx = (cth * dx - sth * dy) * isc + 0.5f * (HB - 1);
    float ly = (sth * dx + cth * dy) * isc + 0.5f * (HB - 1);
    // Exact zero-contribution skip (bilinear w/ zero padding vanishes outside (-1, 64)).
    if (lx <= -1.f || lx >= (float)HB || ly <= -1.f || ly >= (float)HB) continue;

    float x0f = floorf(lx), y0f = floorf(ly);
    float wx = lx - x0f, wy = ly - y0f;
    int x0 = (int)x0f, y0 = (int)y0f;
    int x1i = x0 + 1, y1i = y0 + 1;
    bool xv0 = (x0  >= 0) && (x0  < HB);
    bool xv1 = (x1i >= 0) && (x1i < HB);
    bool yv0 = (y0  >= 0) && (y0  < HB);
    bool yv1 = (y1i >= 0) && (y1i < HB);
    int xc0 = min(max(x0,  0), HB - 1);
    int xc1 = min(max(x1i, 0), HB - 1);
    int yc0 = min(max(y0,  0), HB - 1);
    int yc1 = min(max(y1i, 0), HB - 1);
    float f00 = (xv0 && yv0) ? 1.f : 0.f;
    float f01 = (xv1 && yv0) ? 1.f : 0.f;
    float f10 = (xv0 && yv1) ? 1.f : 0.f;
    float f11 = (xv1 && yv1) ? 1.f : 0.f;
    float v00 = sA[yc0][xc0] * f00;
    float v01 = sA[yc0][xc1] * f01;
    float v10 = sA[yc1][xc0] * f10;
    float v11 = sA[yc1][xc1] * f11;
    float w00 = (1.f - wx) * (1.f - wy);
    float w01 = wx * (1.f - wy);
    float w10 = (1.f - wx) * wy;
    float w11 = wx * wy;
    float asamp = v00 * w00 + v01 * w01 + v10 * w10 + v11 * w11;
    float aa    = ca * asamp;                       // sprite alpha
    float wsum  = f00 * w00 + f01 * w01 + f10 * w10 + f11 * w11;  // rgb coverage
    float om = 1.f - aa;
    g0 = g0 * om + (1.f - cr * wsum) * aa;
    g1 = g1 * om + (1.f - cg * wsum) * aa;
    g2 = g2 * om + (1.f - cb * wsum) * aa;
  }
  out[base]             = 1.f - g0;
  out[base + plane]     = 1.f - g1;
  out[base + 2 * plane] = 1.f - g2;
  out[base + 3 * plane] = i3;
}

extern "C" void kernel_launch(void* const* d_in, const int* in_sizes, int n_in,
                              void* d_out, int out_size, void* d_ws, size_t ws_size,
                              hipStream_t stream) {
  const float* images = (const float*)d_in[0];   // (B,4,H,W) f32
  const float* traj   = (const float*)d_in[1];   // (B,4,N)   f32
  const float* colors = (const float*)d_in[2];   // (B,4)     f32
  const float* brush  = (const float*)d_in[3];   // (4,HB,HB) f32
  float* outp   = (float*)d_out;                 // (B,4,H,W) f32
  float* params = (float*)d_ws;                  // B*N*8 floats

  spline_kernel<<<BATCH, 64, 0, stream>>>(traj, params);
  paint_kernel<<<dim3(IMW / TW, IMH / TH, BATCH), 256, 0, stream>>>(
      images, params, colors, brush, outp);
}

// Round 2
// 19.448 us; speedup vs baseline: 1.5402x; 1.5402x over previous
//
#include <hip/hip_runtime.h>
#include <math.h>

#define BATCH 4
#define NPTS  32
#define IMH   512
#define IMW   512
#define HB    64
#define TPW   128   // tile width in pixels (32 threads x 4 px)
#define TH    8     // tile height in pixels

// Single fused kernel.
// Wave 0 of each block: natural-cubic-spline (Thomas via shuffles, lane k = node k),
// per-stroke pose/cull params in registers, ballot-compaction of strokes passing the
// block bbox cull into LDS (order preserving -> compositing order exact).
// Waves 1-3: stage 16KB brush alpha into LDS concurrently. One __syncthreads.
// Then: every thread composites 4 pixels (float4 I/O) over the compacted stroke list.
__global__ __launch_bounds__(256) void fused_paint_kernel(
    const float* __restrict__ images, const float* __restrict__ traj,
    const float* __restrict__ colors, const float* __restrict__ brush,
    float* __restrict__ out) {
  __shared__ float sA[HB][HB + 1];   // brush alpha, padded stride
  __shared__ float spc[NPTS][6];     // compacted: {x, y, cos, sin, 1/scale}
  __shared__ int scount;

  int b = blockIdx.z;
  int t = threadIdx.x;
  int tx = t & 31, ty = t >> 5;
  int c0 = blockIdx.x * TPW, r0 = blockIdx.y * TH;
  int col = c0 + tx * 4, row = r0 + ty;
  size_t plane = (size_t)IMH * IMW;
  size_t base = (size_t)b * 4 * plane + (size_t)row * IMW + col;

  // Issue image loads early (fill HBM latency under spline/staging).
  float4 v0 = *(const float4*)(images + base);
  float4 v1 = *(const float4*)(images + base + plane);
  float4 v2 = *(const float4*)(images + base + 2 * plane);
  float4 v3 = *(const float4*)(images + base + 3 * plane);
  // Uniform color loads (scalarized by compiler).
  float cr = colors[b * 4 + 0], cg = colors[b * 4 + 1];
  float cb = colors[b * 4 + 2], ca = colors[b * 4 + 3];

  if (t >= 64) {
    // ---- waves 1..3: stage brush alpha ----
    for (int i = t - 64; i < HB * HB; i += 192)
      sA[i >> 6][i & (HB - 1)] = brush[3 * HB * HB + i];
  } else {
    // ---- wave 0: spline + cull + compaction ----
    int lane = t;
    const float* tb = traj + b * 4 * NPTS;
    float tsv = 0.f, xv = 0.f, yv = 0.f, zv = 0.f;
    if (lane < NPTS) {
      tsv = tb[0 * NPTS + lane];
      xv  = tb[1 * NPTS + lane];
      yv  = tb[2 * NPTS + lane];
      zv  = tb[3 * NPTS + lane];
    }
    float ts1 = __shfl_down(tsv, 1);
    float x1  = __shfl_down(xv, 1);
    float y1  = __shfl_down(yv, 1);
    float hv  = ts1 - tsv;
    float sxv = (x1 - xv) / hv;
    float syv = (y1 - yv) / hv;

    // Thomas forward sweep, interior i = 1..30 (M[0]=M[31]=0).
    float cpv = 0.f, ddx = 0.f, ddy = 0.f;
    float cp_prev = 0.f, dx_prev = 0.f, dy_prev = 0.f;
    for (int i = 1; i <= NPTS - 2; ++i) {
      float a  = __shfl(hv, i - 1);
      float hi = __shfl(hv, i);
      float rx = 6.0f * (__shfl(sxv, i) - __shfl(sxv, i - 1));
      float ry = 6.0f * (__shfl(syv, i) - __shfl(syv, i - 1));
      float bb = 2.0f * (a + hi);
      float m  = bb - a * cp_prev;
      float cpi = hi / m;
      float dxi = (rx - a * dx_prev) / m;
      float dyi = (ry - a * dy_prev) / m;
      if (lane == i) { cpv = cpi; ddx = dxi; ddy = dyi; }
      cp_prev = cpi; dx_prev = dxi; dy_prev = dyi;
    }
    // Back substitution.
    float Mxv = 0.f, Myv = 0.f;
    float mx_next = 0.f, my_next = 0.f;
    for (int i = NPTS - 2; i >= 1; --i) {
      float cpi = __shfl(cpv, i);
      float dxi = __shfl(ddx, i);
      float dyi = __shfl(ddy, i);
      float mxi = dxi - cpi * mx_next;
      float myi = dyi - cpi * my_next;
      if (lane == i) { Mxv = mxi; Myv = myi; }
      mx_next = mxi; my_next = myi;
    }
    // Node derivatives (uniform shuffles before divergence).
    float Mx1  = __shfl_down(Mxv, 1);
    float My1  = __shfl_down(Myv, 1);
    float sx30 = __shfl(sxv, NPTS - 2);
    float sy30 = __shfl(syv, NPTS - 2);
    float h30  = __shfl(hv,  NPTS - 2);
    float Mx30 = __shfl(Mxv, NPTS - 2);
    float My30 = __shfl(Myv, NPTS - 2);
    float Mx31 = __shfl(Mxv, NPTS - 1);
    float My31 = __shfl(Myv, NPTS - 1);

    float dX, dY;
    if (lane < NPTS - 1) {
      dX = sxv - hv * (2.0f * Mxv + Mx1) / 6.0f;
      dY = syv - hv * (2.0f * Myv + My1) / 6.0f;
    } else {
      dX = sx30 + h30 * (2.0f * Mx31 + Mx30) / 6.0f;
      dY = sy30 + h30 * (2.0f * My31 + My30) / 6.0f;
    }

    bool pred = false;
    float cth = 1.f, sth = 0.f, iscale = 1.f;
    if (lane < NPTS) {
      float r2 = dX * dX + dY * dY;
      if (r2 > 0.f) { float inv = 1.0f / sqrtf(r2); cth = dX * inv; sth = -dY * inv; }
      float scale = fminf(fmaxf(zv, 0.001f), 1.0f);
      iscale = 1.0f / scale;
      float R = scale * 47.4f + 1.5f;  // conservative: exact-zero outside 45.97*scale
      bool active = (zv > 0.f);
      pred = active &&
             (xv + R >= (float)c0) && (xv - R <= (float)(c0 + TPW - 1)) &&
             (yv + R >= (float)r0) && (yv - R <= (float)(r0 + TH - 1));
    }
    unsigned long long m = __ballot(pred);
    if (pred) {
      int pos = __popcll(m & ((1ull << lane) - 1ull));  // order-preserving
      spc[pos][0] = xv;
      spc[pos][1] = yv;
      spc[pos][2] = cth;
      spc[pos][3] = sth;
      spc[pos][4] = iscale;
    }
    if (lane == 0) scount = (int)__popcll(m);
  }
  __syncthreads();

  float gr[4], gg[4], gb[4];
  gr[0] = 1.f - v0.x; gr[1] = 1.f - v0.y; gr[2] = 1.f - v0.z; gr[3] = 1.f - v0.w;
  gg[0] = 1.f - v1.x; gg[1] = 1.f - v1.y; gg[2] = 1.f - v1.z; gg[3] = 1.f - v1.w;
  gb[0] = 1.f - v2.x; gb[1] = 1.f - v2.y; gb[2] = 1.f - v2.z; gb[3] = 1.f - v2.w;

  int cnt = scount;
  float fry = (float)row;

  #pragma unroll 1
  for (int j = 0; j < cnt; ++j) {
    float px  = spc[j][0], py  = spc[j][1];
    float cth = spc[j][2], sth = spc[j][3], isc = spc[j][4];
    float dy = fry - py;
    #pragma unroll
    for (int i = 0; i < 4; ++i) {
      float dx = (float)(col + i) - px;
      float lx = (cth * dx - sth * dy) * isc + 0.5f * (HB - 1);
      float ly = (sth * dx + cth * dy) * isc + 0.5f * (HB - 1);
      if (lx <= -1.f || lx >= (float)HB || ly <= -1.f || ly >= (float)HB) continue;
      float x0f = floorf(lx), y0f = floorf(ly);
      float wx = lx - x0f, wy = ly - y0f;
      int x0 = (int)x0f, y0 = (int)y0f;
      int x1i = x0 + 1, y1i = y0 + 1;
      bool xv0 = (x0  >= 0) && (x0  < HB);
      bool xv1 = (x1i >= 0) && (x1i < HB);
      bool yv0 = (y0  >= 0) && (y0  < HB);
      bool yv1 = (y1i >= 0) && (y1i < HB);
      int xc0 = min(max(x0,  0), HB - 1);
      int xc1 = min(max(x1i, 0), HB - 1);
      int yc0 = min(max(y0,  0), HB - 1);
      int yc1 = min(max(y1i, 0), HB - 1);
      float f00 = (xv0 && yv0) ? 1.f : 0.f;
      float f01 = (xv1 && yv0) ? 1.f : 0.f;
      float f10 = (xv0 && yv1) ? 1.f : 0.f;
      float f11 = (xv1 && yv1) ? 1.f : 0.f;
      float v00 = sA[yc0][xc0] * f00;
      float v01 = sA[yc0][xc1] * f01;
      float v10 = sA[yc1][xc0] * f10;
      float v11 = sA[yc1][xc1] * f11;
      float w00 = (1.f - wx) * (1.f - wy);
      float w01 = wx * (1.f - wy);
      float w10 = (1.f - wx) * wy;
      float w11 = wx * wy;
      float asamp = v00 * w00 + v01 * w01 + v10 * w10 + v11 * w11;
      float aa    = ca * asamp;                                      // sprite alpha
      float wsum  = f00 * w00 + f01 * w01 + f10 * w10 + f11 * w11;   // rgb coverage
      float om = 1.f - aa;
      gr[i] = gr[i] * om + (1.f - cr * wsum) * aa;
      gg[i] = gg[i] * om + (1.f - cg * wsum) * aa;
      gb[i] = gb[i] * om + (1.f - cb * wsum) * aa;
    }
  }

  float4 o0 = make_float4(1.f - gr[0], 1.f - gr[1], 1.f - gr[2], 1.f - gr[3]);
  float4 o1 = make_float4(1.f - gg[0], 1.f - gg[1], 1.f - gg[2], 1.f - gg[3]);
  float4 o2 = make_float4(1.f - gb[0], 1.f - gb[1], 1.f - gb[2], 1.f - gb[3]);
  *(float4*)(out + base)             = o0;
  *(float4*)(out + base + plane)     = o1;
  *(float4*)(out + base + 2 * plane) = o2;
  *(float4*)(out + base + 3 * plane) = v3;
}

extern "C" void kernel_launch(void* const* d_in, const int* in_sizes, int n_in,
                              void* d_out, int out_size, void* d_ws, size_t ws_size,
                              hipStream_t stream) {
  const float* images = (const float*)d_in[0];   // (B,4,H,W) f32
  const float* traj   = (const float*)d_in[1];   // (B,4,N)   f32
  const float* colors = (const float*)d_in[2];   // (B,4)     f32
  const float* brush  = (const float*)d_in[3];   // (4,HB,HB) f32
  float* outp = (float*)d_out;                   // (B,4,H,W) f32

  fused_paint_kernel<<<dim3(IMW / TPW, IMH / TH, BATCH), 256, 0, stream>>>(
      images, traj, colors, brush, outp);
}